// Round 3
// baseline (580.272 us; speedup 1.0000x reference)
//
#include <hip/hip_runtime.h>
#include <stdint.h>

#define BB 2
#define NN 4160
#define CC 512
#define HIDD 2048
#define HH 4096
#define QSCALE 0.12751742f   // log2(e)/sqrt(128), folded into Q epilogue
#define KSPLIT 7
#define KTILES 19            // key tiles (of 32) per split; 7*19 >= 130
#define NKT 130              // total key tiles of 32 (130*32 = 4160)

typedef short bf16x8 __attribute__((ext_vector_type(8)));
typedef float f32x4 __attribute__((ext_vector_type(4)));
typedef float f32x16 __attribute__((ext_vector_type(16)));

__device__ __forceinline__ float bf2f(ushort u){
  union { uint32_t u32; float f; } c; c.u32 = ((uint32_t)u) << 16; return c.f;
}
__device__ __forceinline__ ushort f2bf(float f){
  union { float f; uint32_t u32; } c; c.f = f;
  uint32_t r = c.u32 + 0x7fffu + ((c.u32 >> 16) & 1u);
  return (ushort)(r >> 16);
}
__device__ __forceinline__ float gelu_f(float x){
  return 0.5f * x * (1.0f + erff(x * 0.70710678118654752440f));
}
// async global->LDS, 16B per lane; lds ptr must be wave-uniform-base + lane*16
__device__ __forceinline__ void async16(ushort* lds, const ushort* g){
  __builtin_amdgcn_global_load_lds(
      (const __attribute__((address_space(1))) uint32_t*)g,
      (__attribute__((address_space(3))) uint32_t*)lds, 16, 0, 0);
}
// pack two f32 -> one dword of 2 bf16 (RNE), lo from a, hi from b
__device__ __forceinline__ uint32_t cvtpk_bf16(float a, float b){
  uint32_t r;
  asm("v_cvt_pk_bf16_f32 %0, %1, %2" : "=v"(r) : "v"(a), "v"(b));
  return r;
}
// swap upper 32 lanes of x with lower 32 lanes of y (both modified)
__device__ __forceinline__ void swap32(uint32_t& x, uint32_t& y){
  asm("v_permlane32_swap_b32 %0, %1" : "+v"(x), "+v"(y));
}

template<int MODE>
__device__ __forceinline__ int rowmap(int m){
  if (MODE == 0) return m;                              // identity
  if (MODE == 1) return (m >> 12) * NN + (m & 4095);    // seq rows (H=4096)
  return (m >> 6) * NN + HH + (m & 63);                 // sem rows (64/batch)
}

// ---------------- weights fp32 -> bf16 (one contiguous bf16 arena) ----------------
__global__ __launch_bounds__(256) void wconv_kernel(
    const float* __restrict__ s0, const float* __restrict__ s1,
    const float* __restrict__ s2, const float* __restrict__ s3,
    const float* __restrict__ s4, const float* __restrict__ s5,
    const float* __restrict__ s6, ushort* __restrict__ dst)
{
  int i4 = (blockIdx.x * 256 + threadIdx.x) * 4;
  const float* s; int off;
  if      (i4 <  262144){ s = s0; off = 0;       }
  else if (i4 <  786432){ s = s1; off = 262144;  }
  else if (i4 < 1048576){ s = s2; off = 786432;  }
  else if (i4 < 2097152){ s = s3; off = 1048576; }
  else if (i4 < 3145728){ s = s4; off = 2097152; }
  else if (i4 < 3670016){ s = s5; off = 3145728; }
  else                  { s = s6; off = 3670016; }
  float4 v = *(const float4*)(s + (i4 - off));
  union { ushort h[4]; uint2 u; } o;
  o.h[0] = f2bf(v.x); o.h[1] = f2bf(v.y); o.h[2] = f2bf(v.z); o.h[3] = f2bf(v.w);
  *(uint2*)(dst + i4) = o.u;
}

// ---------------- LayerNorm over C=512, one wave per row, bf16 out ----------------
__global__ __launch_bounds__(256) void ln_kernel(
    const float* __restrict__ x, const float* __restrict__ w,
    const float* __restrict__ b, ushort* __restrict__ out)
{
  int row  = blockIdx.x * 4 + (threadIdx.x >> 6);
  int lane = threadIdx.x & 63;
  const float4* xr = (const float4*)(x + (size_t)row * CC);
  float4 v0 = xr[lane];
  float4 v1 = xr[lane + 64];
  float s  = v0.x + v0.y + v0.z + v0.w + v1.x + v1.y + v1.z + v1.w;
  float ss = v0.x*v0.x + v0.y*v0.y + v0.z*v0.z + v0.w*v0.w
           + v1.x*v1.x + v1.y*v1.y + v1.z*v1.z + v1.w*v1.w;
  #pragma unroll
  for (int off = 1; off < 64; off <<= 1){
    s  += __shfl_xor(s, off);
    ss += __shfl_xor(ss, off);
  }
  float mu  = s * (1.0f / CC);
  float var = ss * (1.0f / CC) - mu * mu;
  float rs  = rsqrtf(var + 1e-5f);
  const float4* wp = (const float4*)w;
  const float4* bp = (const float4*)b;
  float4 w0 = wp[lane], w1 = wp[lane + 64], b0 = bp[lane], b1 = bp[lane + 64];
  union { ushort h[4]; uint2 u; } o0, o1;
  o0.h[0] = f2bf((v0.x - mu) * rs * w0.x + b0.x);
  o0.h[1] = f2bf((v0.y - mu) * rs * w0.y + b0.y);
  o0.h[2] = f2bf((v0.z - mu) * rs * w0.z + b0.z);
  o0.h[3] = f2bf((v0.w - mu) * rs * w0.w + b0.w);
  o1.h[0] = f2bf((v1.x - mu) * rs * w1.x + b1.x);
  o1.h[1] = f2bf((v1.y - mu) * rs * w1.y + b1.y);
  o1.h[2] = f2bf((v1.z - mu) * rs * w1.z + b1.z);
  o1.h[3] = f2bf((v1.w - mu) * rs * w1.w + b1.w);
  ushort* orow = out + (size_t)row * CC;
  ((uint2*)orow)[lane]      = o0.u;
  ((uint2*)orow)[lane + 64] = o1.u;
}

// ---------------- GEMM: out = A(MxK) @ W(OxK)^T + bias; BM=128, BK=64 ------------
// (round-3 verified version: global_load_lds staging, swizzled LDS)
// EPI 0: bf16 store   EPI 1: bf16(gelu)   EPI 2: outf = resid + gamma*(acc+bias)
// EPI 3: fused QKV: col<512 -> qb*QSCALE; col<1024 -> kb; else -> vt transposed
template<int BN, int AMAP, int OMAP, int EPI>
__global__ __launch_bounds__(256) void gemm_kernel(
    const ushort* __restrict__ A, int lda,
    const ushort* __restrict__ W,
    const float* __restrict__ bias, const float* __restrict__ bias2,
    ushort* __restrict__ outb, ushort* __restrict__ outb2,
    float* __restrict__ outf,
    const float* __restrict__ resid, const float* __restrict__ gamma,
    ushort* __restrict__ vt, int K, int O)
{
  constexpr int NCT = BN / 32;           // col 16-tiles per wave
  __shared__ __align__(16) ushort As[128 * 64];
  __shared__ __align__(16) ushort Ws[BN * 64];
  int tid  = threadIdx.x;
  int lane = tid & 63;
  int wv   = tid >> 6;
  int w0   = wv & 1, w1 = wv >> 1;
  int quad = lane >> 4, l16 = lane & 15;
  int m0 = blockIdx.x * 128;
  int o0 = blockIdx.y * BN;

  f32x4 acc[4][NCT];
  f32x4 zf = {0.f, 0.f, 0.f, 0.f};
  #pragma unroll
  for (int i = 0; i < 4; i++)
    #pragma unroll
    for (int j = 0; j < NCT; j++) acc[i][j] = zf;

  for (int k0 = 0; k0 < K; k0 += 64){
    __syncthreads();   // previous tile's ds_reads done before overwrite
    #pragma unroll
    for (int i = 0; i < 4; i++){
      int o = i * 256 + tid;
      int row = o >> 3, c = (o & 7) ^ (row & 7);
      int gm = rowmap<AMAP>(m0 + row);
      async16(&As[o * 8], A + (size_t)gm * lda + k0 + c * 8);
    }
    #pragma unroll
    for (int i = 0; i < BN * 8 / 256; i++){
      int o = i * 256 + tid;
      int row = o >> 3, c = (o & 7) ^ (row & 7);
      async16(&Ws[o * 8], W + (size_t)(o0 + row) * K + k0 + c * 8);
    }
    __syncthreads();   // drain global_load_lds
    #pragma unroll
    for (int kk = 0; kk < 2; kk++){
      bf16x8 af[4], bfr[NCT];
      #pragma unroll
      for (int rt = 0; rt < 4; rt++){
        int row = w1 * 64 + rt * 16 + l16;
        af[rt] = *(const bf16x8*)&As[(row * 8 + ((kk * 4 + quad) ^ (row & 7))) * 8];
      }
      #pragma unroll
      for (int ct = 0; ct < NCT; ct++){
        int row = w0 * (BN / 2) + ct * 16 + l16;
        bfr[ct] = *(const bf16x8*)&Ws[(row * 8 + ((kk * 4 + quad) ^ (row & 7))) * 8];
      }
      #pragma unroll
      for (int rt = 0; rt < 4; rt++)
        #pragma unroll
        for (int ct = 0; ct < NCT; ct++)
          acc[rt][ct] = __builtin_amdgcn_mfma_f32_16x16x32_bf16(af[rt], bfr[ct], acc[rt][ct], 0, 0, 0);
    }
  }

  #pragma unroll
  for (int ct = 0; ct < NCT; ct++){
    int col = o0 + w0 * (BN / 2) + ct * 16 + l16;
    #pragma unroll
    for (int rt = 0; rt < 4; rt++){
      int mb = m0 + w1 * 64 + rt * 16 + quad * 4;
      if (EPI == 3){
        if (col < 512){
          float bs = bias[col];
          #pragma unroll
          for (int r = 0; r < 4; r++)
            outb[(size_t)(mb + r) * 512 + col] = f2bf((acc[rt][ct][r] + bs) * QSCALE);
        } else if (col < 1024){
          float bs = bias2[col - 512];
          #pragma unroll
          for (int r = 0; r < 4; r++)
            outb2[(size_t)(mb + r) * 512 + (col - 512)] = f2bf(acc[rt][ct][r] + bs);
        } else {
          float bs = bias2[col - 512];
          int dd = col - 1024;
          int h2 = dd >> 7, d = dd & 127;
          int bbat = (mb >= NN) ? 1 : 0;
          int n = mb - bbat * NN;
          union { ushort h[4]; uint2 u; } pk;
          #pragma unroll
          for (int r = 0; r < 4; r++) pk.h[r] = f2bf(acc[rt][ct][r] + bs);
          *(uint2*)&vt[((size_t)((bbat * 4 + h2) * 128 + d)) * NN + n] = pk.u;
        }
      } else {
        float bs = bias[col];
        #pragma unroll
        for (int r = 0; r < 4; r++){
          float v = acc[rt][ct][r] + bs;
          if (EPI == 1) v = gelu_f(v);
          if (EPI == 0 || EPI == 1){
            outb[(size_t)rowmap<OMAP>(mb + r) * O + col] = f2bf(v);
          } else {
            size_t off = (size_t)rowmap<OMAP>(mb + r) * O + col;
            outf[off] = resid[off] + gamma[col] * v;
          }
        }
      }
    }
  }
}

// ---------------- flash attention, split-K partials --------------------------------
// Round-2: KVBLK 64 -> 32 for occupancy. LDS 66 KB -> 33 KB => 4 blocks/CU
// (16 waves, enforced __launch_bounds__(256,4)); grid retuned KSPLIT=7 (1848
// blocks on 1024 resident slots = 2 quantized rounds x 19 tiles, vs 4 x 11
// before). 2-phase global_load_lds pipeline + swapped-QK^T in-register softmax
// kept from rounds 0-1 (verified). fmax/sum chains tree-ified (dep depth 4).
__global__ __launch_bounds__(256, 4) void attn_kernel(
    const ushort* __restrict__ q, const ushort* __restrict__ kbuf,
    const ushort* __restrict__ vt, ushort* __restrict__ opart, float* __restrict__ ml)
{
  __shared__ __align__(16) ushort Ks[2][32 * 128];    // [row][c16^(row&7)]
  __shared__ __align__(16) ushort VTs[2][128 * 32];   // [d][c8^(d&3)]
  __shared__ float Als[4][32];                        // per-wave alpha broadcast
  int tid = threadIdx.x, lane = tid & 63, wv = tid >> 6;
  int l31 = lane & 31, hf = lane >> 5;
  int qt = blockIdx.x, bh = blockIdx.y, ks = blockIdx.z;
  int b = bh >> 2, h = bh & 3;
  int jt0 = ks * KTILES;
  int jt1 = jt0 + KTILES; if (jt1 > NKT) jt1 = NKT;

  const ushort* kg0 = kbuf + ((size_t)b * NN) * CC + h * 128;
  const ushort* vg0 = vt + ((size_t)bh * 128) * NN;

  // stage key-tile t (32 keys) into buffer bsel (async DMA, source pre-swizzled)
  auto stage = [&](int bsel, int t){
    const ushort* kgb = kg0 + (size_t)(t * 32) * CC;
    const ushort* vgb = vg0 + t * 32;
    #pragma unroll
    for (int i = 0; i < 2; i++){
      int oo = i * 256 + tid;                    // [0,512)
      int row = oo >> 4, ck = (oo & 15) ^ (row & 7);
      async16(&Ks[bsel][oo * 8], kgb + (size_t)row * CC + ck * 8);
      int d = oo >> 2, cv = (oo & 3) ^ (d & 3);
      async16(&VTs[bsel][oo * 8], vgb + (size_t)d * NN + cv * 8);
    }
  };

  stage(0, jt0);   // prologue; drained by first in-loop barrier

  // Q fragments (B-operand): lane holds q-col = l31, k = kk*16 + hf*8 + e
  int qr = qt * 128 + wv * 32 + l31;
  qr = (qr < NN) ? qr : (NN - 1);
  const ushort* qrow = q + ((size_t)(b * NN + qr)) * CC + h * 128 + hf * 8;
  bf16x8 qf[8];
  #pragma unroll
  for (int kk = 0; kk < 8; kk++)
    qf[kk] = *(const bf16x8*)(qrow + kk * 16);

  float mrow = -1e30f, lrow = 0.f;
  f32x16 o[4];
  #pragma unroll
  for (int dt = 0; dt < 4; dt++)
    #pragma unroll
    for (int r = 0; r < 16; r++) o[dt][r] = 0.f;

  int cur = 0;
  for (int jt = jt0; jt < jt1; jt++){
    __syncthreads();   // buf[cur] staged (vmcnt drain) + prev compute done
    if (jt + 1 < jt1) stage(cur ^ 1, jt + 1);   // in flight across compute
    const ushort* Kb = Ks[cur];
    const ushort* Vb = VTs[cur];

    // S^T = K Q^T : one 32-key subtile, output col = q = l31
    f32x16 s0;
    #pragma unroll
    for (int r = 0; r < 16; r++) s0[r] = 0.f;
    __builtin_amdgcn_s_setprio(1);
    #pragma unroll
    for (int kk = 0; kk < 8; kk++){
      int r0 = l31;
      bf16x8 kf0 = *(const bf16x8*)&Kb[(r0 * 16 + ((kk * 2 + hf) ^ (r0 & 7))) * 8];
      s0 = __builtin_amdgcn_mfma_f32_32x32x16_bf16(kf0, qf[kk], s0, 0, 0, 0);
    }
    __builtin_amdgcn_s_setprio(0);

    // in-register online softmax (exp2 domain); lane pair shares q = l31
    float mx = fmaxf(
        fmaxf(fmaxf(fmaxf(s0[0], s0[1]),  fmaxf(s0[2],  s0[3])),
              fmaxf(fmaxf(s0[4], s0[5]),  fmaxf(s0[6],  s0[7]))),
        fmaxf(fmaxf(fmaxf(s0[8], s0[9]),  fmaxf(s0[10], s0[11])),
              fmaxf(fmaxf(s0[12], s0[13]), fmaxf(s0[14], s0[15]))));
    mx = fmaxf(mx, __shfl_xor(mx, 32));

    if (__any(mx > mrow + 8.0f)){        // defer-max: rescale only when needed
      float mn = fmaxf(mrow, mx);
      float al = __builtin_amdgcn_exp2f(mrow - mn);
      mrow = mn;
      lrow *= al;
      if (lane < 32) Als[wv][l31] = al;  // per-wave broadcast (LDS ops in-order)
      #pragma unroll
      for (int g = 0; g < 4; g++){
        float4 ag = *(const float4*)&Als[wv][8 * g + 4 * hf];
        float agr[4] = {ag.x, ag.y, ag.z, ag.w};
        #pragma unroll
        for (int dt = 0; dt < 4; dt++)
          #pragma unroll
          for (int r = 0; r < 4; r++)
            o[dt][4 * g + r] *= agr[r];
      }
    }

    #pragma unroll
    for (int r = 0; r < 16; r++) s0[r] = __builtin_amdgcn_exp2f(s0[r] - mrow);
    float t = (((s0[0] + s0[1]) + (s0[2] + s0[3])) + ((s0[4] + s0[5]) + (s0[6] + s0[7])))
            + (((s0[8] + s0[9]) + (s0[10] + s0[11])) + ((s0[12] + s0[13]) + (s0[14] + s0[15])));
    t += __shfl_xor(t, 32);              // lane pair holds disjoint key halves
    lrow += t;

    // P -> A-fragments: 8 cvt_pk + 4 permlane32_swap, no LDS
    union PU { uint32_t w[4]; bf16x8 v; };
    bf16x8 pa[2];
    {
      uint32_t Aw = cvtpk_bf16(s0[0], s0[1]);
      uint32_t Bw = cvtpk_bf16(s0[2], s0[3]);
      uint32_t Cw = cvtpk_bf16(s0[4], s0[5]);
      uint32_t Dw = cvtpk_bf16(s0[6], s0[7]);
      swap32(Aw, Cw); swap32(Bw, Dw);
      PU u0; u0.w[0] = Aw; u0.w[1] = Bw; u0.w[2] = Cw; u0.w[3] = Dw; pa[0] = u0.v;
      uint32_t Ew = cvtpk_bf16(s0[8],  s0[9]);
      uint32_t Fw = cvtpk_bf16(s0[10], s0[11]);
      uint32_t Gw = cvtpk_bf16(s0[12], s0[13]);
      uint32_t Hw = cvtpk_bf16(s0[14], s0[15]);
      swap32(Ew, Gw); swap32(Fw, Hw);
      PU u1; u1.w[0] = Ew; u1.w[1] = Fw; u1.w[2] = Gw; u1.w[3] = Hw; pa[1] = u1.v;
    }

    // O += P V : A = pa (row = q = l31, k = key), B = V^T frag (col = d)
    __builtin_amdgcn_s_setprio(1);
    #pragma unroll
    for (int k4 = 0; k4 < 2; k4++)
      #pragma unroll
      for (int dt = 0; dt < 4; dt++){
        int d = dt * 32 + l31;
        bf16x8 vf = *(const bf16x8*)&Vb[(d * 4 + ((k4 * 2 + hf) ^ (d & 3))) * 8];
        o[dt] = __builtin_amdgcn_mfma_f32_32x32x16_bf16(pa[k4], vf, o[dt], 0, 0, 0);
      }
    __builtin_amdgcn_s_setprio(0);
    cur ^= 1;
  }

  int part = (qt * 8 + bh) * KSPLIT + ks;
  if (lane < 32){
    ml[(size_t)part * 256 + wv * 32 + l31]       = mrow;
    ml[(size_t)part * 256 + 128 + wv * 32 + l31] = lrow;
  }
  // bf16 partials, fully coalesced: group G=(wv*4+g)*4+dt, 4 bf16 per lane =
  // rows q = wv*32 + 8g + 4*hf + (0..3), col d = dt*32 + l31
  ushort* op = opart + (size_t)part * 16384;
  #pragma unroll
  for (int g = 0; g < 4; g++)
    #pragma unroll
    for (int dt = 0; dt < 4; dt++){
      uint2 pk;
      pk.x = cvtpk_bf16(o[dt][4 * g + 0], o[dt][4 * g + 1]);
      pk.y = cvtpk_bf16(o[dt][4 * g + 2], o[dt][4 * g + 3]);
      *(uint2*)&op[((((wv * 4 + g) * 4 + dt) * 64) + lane) * 4] = pk;
    }
}

// ---------------- combine KSPLIT key-split bf16 partials -> bf16 attention out ---
__global__ __launch_bounds__(256) void attn_combine_kernel(
    const ushort* __restrict__ opart, const float* __restrict__ ml,
    ushort* __restrict__ out)
{
  int qt = blockIdx.x, bh = blockIdx.y;
  int b = bh >> 2, hd = bh & 3;
  int tid = threadIdx.x, lane = tid & 63, wq = tid >> 6;
  int l31 = lane & 31, hf = lane >> 5;
  int base = (qt * 8 + bh) * KSPLIT;

  #pragma unroll
  for (int g = 0; g < 4; g++){
    int qb = wq * 32 + 8 * g + 4 * hf;       // 4 consecutive q rows
    float mv[KSPLIT][4], lv[KSPLIT][4];
    #pragma unroll
    for (int p = 0; p < KSPLIT; p++){
      float4 m = *(const float4*)&ml[(size_t)(base + p) * 256 + qb];
      float4 l = *(const float4*)&ml[(size_t)(base + p) * 256 + 128 + qb];
      mv[p][0] = m.x; mv[p][1] = m.y; mv[p][2] = m.z; mv[p][3] = m.w;
      lv[p][0] = l.x; lv[p][1] = l.y; lv[p][2] = l.z; lv[p][3] = l.w;
    }
    float wr[KSPLIT][4], invr[4];
    #pragma unroll
    for (int r = 0; r < 4; r++){
      float mx = mv[0][r];
      #pragma unroll
      for (int p = 1; p < KSPLIT; p++) mx = fmaxf(mx, mv[p][r]);
      float den = 0.f;
      #pragma unroll
      for (int p = 0; p < KSPLIT; p++){
        wr[p][r] = __builtin_amdgcn_exp2f(mv[p][r] - mx);
        den += wr[p][r] * lv[p][r];
      }
      invr[r] = 1.0f / den;
    }
    #pragma unroll
    for (int dt = 0; dt < 4; dt++){
      int idx = (((wq * 4 + g) * 4 + dt) * 64 + lane) * 4;
      float acc[4] = {0.f, 0.f, 0.f, 0.f};
      #pragma unroll
      for (int p = 0; p < KSPLIT; p++){
        union { ushort h[4]; uint2 u; } a;
        a.u = *(const uint2*)&opart[(size_t)(base + p) * 16384 + idx];
        #pragma unroll
        for (int r = 0; r < 4; r++) acc[r] += wr[p][r] * bf2f(a.h[r]);
      }
      #pragma unroll
      for (int r = 0; r < 4; r++){
        int n = qt * 128 + qb + r;
        if (n < NN)
          out[((size_t)(b * NN + n)) * CC + hd * 128 + dt * 32 + l31] = f2bf(acc[r] * invr[r]);
      }
    }
  }
}

// ---------------- depthwise conv k=3 along sequence + exact GELU, bf16 ----------
__global__ __launch_bounds__(256) void dwconv_kernel(
    const ushort* __restrict__ u, const float* __restrict__ w,
    const float* __restrict__ bia, ushort* __restrict__ out)
{
  int g = blockIdx.x * 256 + threadIdx.x;   // 8 channels per thread
  int row = g >> 8;
  int c8 = (g & 255) * 8;
  int n = row & (HH - 1);
  size_t base = (size_t)row * HIDD + c8;
  uint4 z4; z4.x = z4.y = z4.z = z4.w = 0;
  uint4 u1 = *(const uint4*)(u + base);
  uint4 u0 = (n > 0)      ? *(const uint4*)(u + base - HIDD) : z4;
  uint4 u2 = (n < HH - 1) ? *(const uint4*)(u + base + HIDD) : z4;
  const ushort* p0 = (const ushort*)&u0;
  const ushort* p1 = (const ushort*)&u1;
  const ushort* p2 = (const ushort*)&u2;
  union { ushort h[8]; uint4 v; } o;
  #pragma unroll
  for (int k = 0; k < 8; k++){
    int c = c8 + k;
    float acc = bia[c] + w[c * 3] * bf2f(p0[k]) + w[c * 3 + 1] * bf2f(p1[k]) + w[c * 3 + 2] * bf2f(p2[k]);
    o.h[k] = f2bf(gelu_f(acc));
  }
  *(uint4*)(out + base) = o.v;
}

// ---------------- launch ----------------
extern "C" void kernel_launch(void* const* d_in, const int* in_sizes, int n_in,
                              void* d_out, int out_size, void* d_ws, size_t ws_size,
                              hipStream_t stream)
{
  const float* x      = (const float*)d_in[0];
  const float* ln1w   = (const float*)d_in[1];
  const float* ln1b   = (const float*)d_in[2];
  const float* ln2w   = (const float*)d_in[3];
  const float* ln2b   = (const float*)d_in[4];
  const float* q_b    = (const float*)d_in[6];
  const float* kv_b   = (const float*)d_in[8];
  const float* proj_b = (const float*)d_in[10];
  const float* fc1_b  = (const float*)d_in[12];
  const float* dw_w   = (const float*)d_in[13];
  const float* dw_b   = (const float*)d_in[14];
  const float* fc2_b  = (const float*)d_in[16];
  const float* px1_b  = (const float*)d_in[18];
  const float* px2_b  = (const float*)d_in[20];
  const float* gamma1 = (const float*)d_in[21];
  const float* gamma2 = (const float*)d_in[22];
  float* out = (float*)d_out;

  char* ws = (char*)d_ws;
  ushort* wbf = (ushort*)(ws);               //  8,388,608 B  weights bf16
  ushort* lnb = (ushort*)(ws + 8388608);     //  8,519,680 B  ln out
  ushort* qb  = (ushort*)(ws + 16908288);    //  8,519,680 B  Q (pre-scaled)
  ushort* kb  = (ushort*)(ws + 25427968);    //  8,519,680 B  K
  ushort* vtb = (ushort*)(ws + 33947648);    //  8,519,680 B  V^T (bh,d,n)
  ushort* ab  = (ushort*)(ws + 42467328);    //  8,519,680 B  attention out
  // overlay region: opart+ml used by attn/combine, then f1/dg by FFN
  ushort* opart = (ushort*)(ws + 50987008);  // 60,555,264 B (bf16 partials, 7 splits)
  float*  mlb   = (float*)(ws + 111542272);  //  1,892,352 B (ends 113,434,624)
  ushort* f1  = (ushort*)(ws + 50987008);    // 33,554,432 B
  ushort* dg  = (ushort*)(ws + 84541440);    // 33,554,432 B
  ushort* sm1 = (ushort*)(ws + 118095872);   //    262,144 B

  ushort* wq    = wbf;              // also covers wkv at +262144 (fused O=1536)
  ushort* wproj = wbf + 786432;
  ushort* wfc1  = wbf + 1048576;
  ushort* wfc2  = wbf + 2097152;
  ushort* wpx1  = wbf + 3145728;
  ushort* wpx2  = wbf + 3670016;

  wconv_kernel<<<4096, 256, 0, stream>>>((const float*)d_in[5], (const float*)d_in[7],
                                         (const float*)d_in[9], (const float*)d_in[11],
                                         (const float*)d_in[15], (const float*)d_in[17],
                                         (const float*)d_in[19], wbf);
  ln_kernel<<<2080, 256, 0, stream>>>(x, ln1w, ln1b, lnb);
  // fused QKV: O = 1536 (q_w ++ kv_w are adjacent in wbf)
  gemm_kernel<128,0,0,3><<<dim3(65, 12), 256, 0, stream>>>(
      lnb, 512, wq, q_b, kv_b, qb, kb, nullptr, nullptr, nullptr, vtb, 512, 1536);
  attn_kernel<<<dim3(33, 8, KSPLIT), 256, 0, stream>>>(qb, kb, vtb, opart, mlb);
  attn_combine_kernel<<<dim3(33, 8), 256, 0, stream>>>(opart, mlb, ab);
  gemm_kernel<64,0,0,2><<<dim3(65, 8), 256, 0, stream>>>(
      ab, 512, wproj, proj_b, nullptr, nullptr, nullptr, out, x, gamma1, nullptr, 512, 512);
  ln_kernel<<<2080, 256, 0, stream>>>(out, ln2w, ln2b, lnb);
  gemm_kernel<128,1,0,0><<<dim3(64, 16), 256, 0, stream>>>(
      lnb, 512, wfc1, fc1_b, nullptr, f1, nullptr, nullptr, nullptr, nullptr, nullptr, 512, 2048);
  dwconv_kernel<<<8192, 256, 0, stream>>>(f1, dw_w, dw_b, dg);
  gemm_kernel<64,0,1,2><<<dim3(64, 8), 256, 0, stream>>>(
      dg, 2048, wfc2, fc2_b, nullptr, nullptr, nullptr, out, out, gamma2, nullptr, 2048, 512);
  gemm_kernel<64,2,0,1><<<dim3(1, 16), 256, 0, stream>>>(
      lnb, 512, wpx1, px1_b, nullptr, sm1, nullptr, nullptr, nullptr, nullptr, nullptr, 512, 1024);
  gemm_kernel<64,0,2,2><<<dim3(1, 8), 256, 0, stream>>>(
      sm1, 1024, wpx2, px2_b, nullptr, nullptr, nullptr, out, out, gamma2, nullptr, 1024, 512);
}

// Round 4
// 456.241 us; speedup vs baseline: 1.2719x; 1.2719x over previous
//
#include <hip/hip_runtime.h>
#include <stdint.h>

#define BB 2
#define NN 4160
#define CC 512
#define HIDD 2048
#define HH 4096
#define QSCALE 0.12751742f   // log2(e)/sqrt(128), folded into Q epilogue
#define KSPLIT 6
#define KTILES 11            // key tiles (of 64) per split; 6*11 >= 65

typedef short bf16x8 __attribute__((ext_vector_type(8)));
typedef float f32x4 __attribute__((ext_vector_type(4)));
typedef float f32x16 __attribute__((ext_vector_type(16)));

__device__ __forceinline__ float bf2f(ushort u){
  union { uint32_t u32; float f; } c; c.u32 = ((uint32_t)u) << 16; return c.f;
}
__device__ __forceinline__ ushort f2bf(float f){
  union { float f; uint32_t u32; } c; c.f = f;
  uint32_t r = c.u32 + 0x7fffu + ((c.u32 >> 16) & 1u);
  return (ushort)(r >> 16);
}
__device__ __forceinline__ float gelu_f(float x){
  return 0.5f * x * (1.0f + erff(x * 0.70710678118654752440f));
}
// async global->LDS, 16B per lane; lds ptr must be wave-uniform-base + lane*16
__device__ __forceinline__ void async16(ushort* lds, const ushort* g){
  __builtin_amdgcn_global_load_lds(
      (const __attribute__((address_space(1))) uint32_t*)g,
      (__attribute__((address_space(3))) uint32_t*)lds, 16, 0, 0);
}
// pack two f32 -> one dword of 2 bf16 (RNE), lo from a, hi from b
__device__ __forceinline__ uint32_t cvtpk_bf16(float a, float b){
  uint32_t r;
  asm("v_cvt_pk_bf16_f32 %0, %1, %2" : "=v"(r) : "v"(a), "v"(b));
  return r;
}
// swap upper 32 lanes of x with lower 32 lanes of y (both modified)
__device__ __forceinline__ void swap32(uint32_t& x, uint32_t& y){
  asm("v_permlane32_swap_b32 %0, %1" : "+v"(x), "+v"(y));
}

template<int MODE>
__device__ __forceinline__ int rowmap(int m){
  if (MODE == 0) return m;                              // identity
  if (MODE == 1) return (m >> 12) * NN + (m & 4095);    // seq rows (H=4096)
  return (m >> 6) * NN + HH + (m & 63);                 // sem rows (64/batch)
}

// ---------------- weights fp32 -> bf16 (one contiguous bf16 arena) ----------------
__global__ __launch_bounds__(256) void wconv_kernel(
    const float* __restrict__ s0, const float* __restrict__ s1,
    const float* __restrict__ s2, const float* __restrict__ s3,
    const float* __restrict__ s4, const float* __restrict__ s5,
    const float* __restrict__ s6, ushort* __restrict__ dst)
{
  int i4 = (blockIdx.x * 256 + threadIdx.x) * 4;
  const float* s; int off;
  if      (i4 <  262144){ s = s0; off = 0;       }
  else if (i4 <  786432){ s = s1; off = 262144;  }
  else if (i4 < 1048576){ s = s2; off = 786432;  }
  else if (i4 < 2097152){ s = s3; off = 1048576; }
  else if (i4 < 3145728){ s = s4; off = 2097152; }
  else if (i4 < 3670016){ s = s5; off = 3145728; }
  else                  { s = s6; off = 3670016; }
  float4 v = *(const float4*)(s + (i4 - off));
  union { ushort h[4]; uint2 u; } o;
  o.h[0] = f2bf(v.x); o.h[1] = f2bf(v.y); o.h[2] = f2bf(v.z); o.h[3] = f2bf(v.w);
  *(uint2*)(dst + i4) = o.u;
}

// ---------------- LayerNorm over C=512, one wave per row, bf16 out ----------------
__global__ __launch_bounds__(256) void ln_kernel(
    const float* __restrict__ x, const float* __restrict__ w,
    const float* __restrict__ b, ushort* __restrict__ out)
{
  int row  = blockIdx.x * 4 + (threadIdx.x >> 6);
  int lane = threadIdx.x & 63;
  const float4* xr = (const float4*)(x + (size_t)row * CC);
  float4 v0 = xr[lane];
  float4 v1 = xr[lane + 64];
  float s  = v0.x + v0.y + v0.z + v0.w + v1.x + v1.y + v1.z + v1.w;
  float ss = v0.x*v0.x + v0.y*v0.y + v0.z*v0.z + v0.w*v0.w
           + v1.x*v1.x + v1.y*v1.y + v1.z*v1.z + v1.w*v1.w;
  #pragma unroll
  for (int off = 1; off < 64; off <<= 1){
    s  += __shfl_xor(s, off);
    ss += __shfl_xor(ss, off);
  }
  float mu  = s * (1.0f / CC);
  float var = ss * (1.0f / CC) - mu * mu;
  float rs  = rsqrtf(var + 1e-5f);
  const float4* wp = (const float4*)w;
  const float4* bp = (const float4*)b;
  float4 w0 = wp[lane], w1 = wp[lane + 64], b0 = bp[lane], b1 = bp[lane + 64];
  union { ushort h[4]; uint2 u; } o0, o1;
  o0.h[0] = f2bf((v0.x - mu) * rs * w0.x + b0.x);
  o0.h[1] = f2bf((v0.y - mu) * rs * w0.y + b0.y);
  o0.h[2] = f2bf((v0.z - mu) * rs * w0.z + b0.z);
  o0.h[3] = f2bf((v0.w - mu) * rs * w0.w + b0.w);
  o1.h[0] = f2bf((v1.x - mu) * rs * w1.x + b1.x);
  o1.h[1] = f2bf((v1.y - mu) * rs * w1.y + b1.y);
  o1.h[2] = f2bf((v1.z - mu) * rs * w1.z + b1.z);
  o1.h[3] = f2bf((v1.w - mu) * rs * w1.w + b1.w);
  ushort* orow = out + (size_t)row * CC;
  ((uint2*)orow)[lane]      = o0.u;
  ((uint2*)orow)[lane + 64] = o1.u;
}

// ---------------- GEMM: out = A(MxK) @ W(OxK)^T + bias; BM=128, BK=64 ------------
// Round-4: T3 2-phase pipeline (same verified recipe as attn round-2 win).
// Double-buffered As/Ws; ONE barrier per K-step; stage of tile k+64 issued AFTER
// the barrier so global_load_lds stays in flight across the whole compute phase
// (previously the second barrier drained the loads immediately -> latency exposed).
// EPI 0: bf16 store   EPI 1: bf16(gelu)   EPI 2: outf = resid + gamma*(acc+bias)
// EPI 3: fused QKV: col<512 -> qb*QSCALE; col<1024 -> kb; else -> vt transposed
template<int BN, int AMAP, int OMAP, int EPI>
__global__ __launch_bounds__(256) void gemm_kernel(
    const ushort* __restrict__ A, int lda,
    const ushort* __restrict__ W,
    const float* __restrict__ bias, const float* __restrict__ bias2,
    ushort* __restrict__ outb, ushort* __restrict__ outb2,
    float* __restrict__ outf,
    const float* __restrict__ resid, const float* __restrict__ gamma,
    ushort* __restrict__ vt, int K, int O)
{
  constexpr int NCT = BN / 32;           // col 16-tiles per wave
  __shared__ __align__(16) ushort As[2][128 * 64];
  __shared__ __align__(16) ushort Ws[2][BN * 64];
  int tid  = threadIdx.x;
  int lane = tid & 63;
  int wv   = tid >> 6;
  int w0   = wv & 1, w1 = wv >> 1;
  int quad = lane >> 4, l16 = lane & 15;
  int m0 = blockIdx.x * 128;
  int o0 = blockIdx.y * BN;

  // stage K-step k0 into buffer bsel (async DMA)
  auto stage = [&](int bsel, int k0){
    #pragma unroll
    for (int i = 0; i < 4; i++){
      int o = i * 256 + tid;
      int row = o >> 3, c = (o & 7) ^ (row & 7);
      int gm = rowmap<AMAP>(m0 + row);
      async16(&As[bsel][o * 8], A + (size_t)gm * lda + k0 + c * 8);
    }
    #pragma unroll
    for (int i = 0; i < BN * 8 / 256; i++){
      int o = i * 256 + tid;
      int row = o >> 3, c = (o & 7) ^ (row & 7);
      async16(&Ws[bsel][o * 8], W + (size_t)(o0 + row) * K + k0 + c * 8);
    }
  };

  f32x4 acc[4][NCT];
  f32x4 zf = {0.f, 0.f, 0.f, 0.f};
  #pragma unroll
  for (int i = 0; i < 4; i++)
    #pragma unroll
    for (int j = 0; j < NCT; j++) acc[i][j] = zf;

  stage(0, 0);   // prologue; drained by first in-loop barrier
  int cur = 0;
  for (int k0 = 0; k0 < K; k0 += 64){
    __syncthreads();   // buf[cur] staged (vmcnt drain) + prev reads done
    if (k0 + 64 < K) stage(cur ^ 1, k0 + 64);   // in flight across compute
    #pragma unroll
    for (int kk = 0; kk < 2; kk++){
      bf16x8 af[4], bfr[NCT];
      #pragma unroll
      for (int rt = 0; rt < 4; rt++){
        int row = w1 * 64 + rt * 16 + l16;
        af[rt] = *(const bf16x8*)&As[cur][(row * 8 + ((kk * 4 + quad) ^ (row & 7))) * 8];
      }
      #pragma unroll
      for (int ct = 0; ct < NCT; ct++){
        int row = w0 * (BN / 2) + ct * 16 + l16;
        bfr[ct] = *(const bf16x8*)&Ws[cur][(row * 8 + ((kk * 4 + quad) ^ (row & 7))) * 8];
      }
      #pragma unroll
      for (int rt = 0; rt < 4; rt++)
        #pragma unroll
        for (int ct = 0; ct < NCT; ct++)
          acc[rt][ct] = __builtin_amdgcn_mfma_f32_16x16x32_bf16(af[rt], bfr[ct], acc[rt][ct], 0, 0, 0);
    }
    cur ^= 1;
  }

  #pragma unroll
  for (int ct = 0; ct < NCT; ct++){
    int col = o0 + w0 * (BN / 2) + ct * 16 + l16;
    #pragma unroll
    for (int rt = 0; rt < 4; rt++){
      int mb = m0 + w1 * 64 + rt * 16 + quad * 4;
      if (EPI == 3){
        if (col < 512){
          float bs = bias[col];
          #pragma unroll
          for (int r = 0; r < 4; r++)
            outb[(size_t)(mb + r) * 512 + col] = f2bf((acc[rt][ct][r] + bs) * QSCALE);
        } else if (col < 1024){
          float bs = bias2[col - 512];
          #pragma unroll
          for (int r = 0; r < 4; r++)
            outb2[(size_t)(mb + r) * 512 + (col - 512)] = f2bf(acc[rt][ct][r] + bs);
        } else {
          float bs = bias2[col - 512];
          int dd = col - 1024;
          int h2 = dd >> 7, d = dd & 127;
          int bbat = (mb >= NN) ? 1 : 0;
          int n = mb - bbat * NN;
          union { ushort h[4]; uint2 u; } pk;
          #pragma unroll
          for (int r = 0; r < 4; r++) pk.h[r] = f2bf(acc[rt][ct][r] + bs);
          *(uint2*)&vt[((size_t)((bbat * 4 + h2) * 128 + d)) * NN + n] = pk.u;
        }
      } else {
        float bs = bias[col];
        #pragma unroll
        for (int r = 0; r < 4; r++){
          float v = acc[rt][ct][r] + bs;
          if (EPI == 1) v = gelu_f(v);
          if (EPI == 0 || EPI == 1){
            outb[(size_t)rowmap<OMAP>(mb + r) * O + col] = f2bf(v);
          } else {
            size_t off = (size_t)rowmap<OMAP>(mb + r) * O + col;
            outf[off] = resid[off] + gamma[col] * v;
          }
        }
      }
    }
  }
}

// ---------------- flash attention, split-K partials --------------------------------
// Round-2 verified configuration (108 us, FETCH 82 MB): KVBLK=64, KSPLIT=6,
// 2 blocks/CU. T3 2-phase global_load_lds pipeline with pre-swizzled source;
// ONE barrier per tile. Swapped-QK^T 32x32 in-register softmax (T12), defer-max
// (T13). Round-3's KVBLK=32 / 4-blocks-CU experiment REGRESSED (FETCH 570 MB:
// cross-block L2 reuse collapsed + half-line V reads) -> reverted exactly.
__global__ __launch_bounds__(256, 2) void attn_kernel(
    const ushort* __restrict__ q, const ushort* __restrict__ kbuf,
    const ushort* __restrict__ vt, ushort* __restrict__ opart, float* __restrict__ ml)
{
  __shared__ __align__(16) ushort Ks[2][64 * 128];    // [row][c16^(row&7)]
  __shared__ __align__(16) ushort VTs[2][128 * 64];   // [d][c8^(d&7)]
  __shared__ float Als[4][32];                        // per-wave alpha broadcast
  int tid = threadIdx.x, lane = tid & 63, wv = tid >> 6;
  int l31 = lane & 31, hf = lane >> 5;
  int qt = blockIdx.x, bh = blockIdx.y, ks = blockIdx.z;
  int b = bh >> 2, h = bh & 3;
  int jt0 = ks * KTILES;
  int jt1 = jt0 + KTILES; if (jt1 > 65) jt1 = 65;

  const ushort* kg0 = kbuf + ((size_t)b * NN) * CC + h * 128;
  const ushort* vg0 = vt + ((size_t)bh * 128) * NN;

  // stage key-tile t into buffer bsel (async DMA, source pre-swizzled)
  auto stage = [&](int bsel, int t){
    const ushort* kgb = kg0 + (size_t)(t * 64) * CC;
    const ushort* vgb = vg0 + t * 64;
    #pragma unroll
    for (int i = 0; i < 4; i++){
      int oo = i * 256 + tid;
      int row = oo >> 4, ck = (oo & 15) ^ (row & 7);
      async16(&Ks[bsel][oo * 8], kgb + (size_t)row * CC + ck * 8);
      int d = oo >> 3, cv = (oo & 7) ^ (d & 7);
      async16(&VTs[bsel][oo * 8], vgb + (size_t)d * NN + cv * 8);
    }
  };

  stage(0, jt0);   // prologue; drained by first in-loop barrier

  // Q fragments (B-operand): lane holds q-col = l31, k = kk*16 + hf*8 + e
  int qr = qt * 128 + wv * 32 + l31;
  qr = (qr < NN) ? qr : (NN - 1);
  const ushort* qrow = q + ((size_t)(b * NN + qr)) * CC + h * 128 + hf * 8;
  bf16x8 qf[8];
  #pragma unroll
  for (int kk = 0; kk < 8; kk++)
    qf[kk] = *(const bf16x8*)(qrow + kk * 16);

  float mrow = -1e30f, lrow = 0.f;
  f32x16 o[4];
  #pragma unroll
  for (int dt = 0; dt < 4; dt++)
    #pragma unroll
    for (int r = 0; r < 16; r++) o[dt][r] = 0.f;

  int cur = 0;
  for (int jt = jt0; jt < jt1; jt++){
    __syncthreads();   // buf[cur] staged (vmcnt drain) + prev compute done
    if (jt + 1 < jt1) stage(cur ^ 1, jt + 1);   // in flight across compute
    const ushort* Kb = Ks[cur];
    const ushort* Vb = VTs[cur];

    // S^T = K Q^T : two 32-key subtiles, output col = q = l31
    f32x16 s0, s1;
    #pragma unroll
    for (int r = 0; r < 16; r++){ s0[r] = 0.f; s1[r] = 0.f; }
    __builtin_amdgcn_s_setprio(1);
    #pragma unroll
    for (int kk = 0; kk < 8; kk++){
      int r0 = l31, r1 = 32 + l31;
      bf16x8 kf0 = *(const bf16x8*)&Kb[(r0 * 16 + ((kk * 2 + hf) ^ (r0 & 7))) * 8];
      bf16x8 kf1 = *(const bf16x8*)&Kb[(r1 * 16 + ((kk * 2 + hf) ^ (r1 & 7))) * 8];
      s0 = __builtin_amdgcn_mfma_f32_32x32x16_bf16(kf0, qf[kk], s0, 0, 0, 0);
      s1 = __builtin_amdgcn_mfma_f32_32x32x16_bf16(kf1, qf[kk], s1, 0, 0, 0);
    }
    __builtin_amdgcn_s_setprio(0);

    // in-register online softmax (exp2 domain); lane pair shares q = l31
    float mx = s0[0];
    #pragma unroll
    for (int r = 1; r < 16; r++) mx = fmaxf(mx, s0[r]);
    #pragma unroll
    for (int r = 0; r < 16; r++) mx = fmaxf(mx, s1[r]);
    mx = fmaxf(mx, __shfl_xor(mx, 32));

    if (__any(mx > mrow + 8.0f)){        // defer-max: rescale only when needed
      float mn = fmaxf(mrow, mx);
      float al = __builtin_amdgcn_exp2f(mrow - mn);
      mrow = mn;
      lrow *= al;
      if (lane < 32) Als[wv][l31] = al;  // per-wave broadcast (LDS ops in-order)
      #pragma unroll
      for (int g = 0; g < 4; g++){
        float4 ag = *(const float4*)&Als[wv][8 * g + 4 * hf];
        float agr[4] = {ag.x, ag.y, ag.z, ag.w};
        #pragma unroll
        for (int dt = 0; dt < 4; dt++)
          #pragma unroll
          for (int r = 0; r < 4; r++)
            o[dt][4 * g + r] *= agr[r];
      }
    }

    float t = 0.f;
    #pragma unroll
    for (int r = 0; r < 16; r++){ s0[r] = __builtin_amdgcn_exp2f(s0[r] - mrow); t += s0[r]; }
    #pragma unroll
    for (int r = 0; r < 16; r++){ s1[r] = __builtin_amdgcn_exp2f(s1[r] - mrow); t += s1[r]; }
    t += __shfl_xor(t, 32);              // lane pair holds disjoint key halves
    lrow += t;

    // P -> A-fragments: 16 cvt_pk + 8 permlane32_swap, no LDS
    union PU { uint32_t w[4]; bf16x8 v; };
    bf16x8 pa[4];
    {
      uint32_t Aw = cvtpk_bf16(s0[0],  s0[1]);
      uint32_t Bw = cvtpk_bf16(s0[2],  s0[3]);
      uint32_t Cw = cvtpk_bf16(s0[4],  s0[5]);
      uint32_t Dw = cvtpk_bf16(s0[6],  s0[7]);
      swap32(Aw, Cw); swap32(Bw, Dw);
      PU u0; u0.w[0] = Aw; u0.w[1] = Bw; u0.w[2] = Cw; u0.w[3] = Dw; pa[0] = u0.v;
      uint32_t Ew = cvtpk_bf16(s0[8],  s0[9]);
      uint32_t Fw = cvtpk_bf16(s0[10], s0[11]);
      uint32_t Gw = cvtpk_bf16(s0[12], s0[13]);
      uint32_t Hw = cvtpk_bf16(s0[14], s0[15]);
      swap32(Ew, Gw); swap32(Fw, Hw);
      PU u1; u1.w[0] = Ew; u1.w[1] = Fw; u1.w[2] = Gw; u1.w[3] = Hw; pa[1] = u1.v;
      uint32_t Iw = cvtpk_bf16(s1[0],  s1[1]);
      uint32_t Jw = cvtpk_bf16(s1[2],  s1[3]);
      uint32_t Kw = cvtpk_bf16(s1[4],  s1[5]);
      uint32_t Lw = cvtpk_bf16(s1[6],  s1[7]);
      swap32(Iw, Kw); swap32(Jw, Lw);
      PU u2; u2.w[0] = Iw; u2.w[1] = Jw; u2.w[2] = Kw; u2.w[3] = Lw; pa[2] = u2.v;
      uint32_t Mw = cvtpk_bf16(s1[8],  s1[9]);
      uint32_t Nw = cvtpk_bf16(s1[10], s1[11]);
      uint32_t Ow = cvtpk_bf16(s1[12], s1[13]);
      uint32_t Pw = cvtpk_bf16(s1[14], s1[15]);
      swap32(Mw, Ow); swap32(Nw, Pw);
      PU u3; u3.w[0] = Mw; u3.w[1] = Nw; u3.w[2] = Ow; u3.w[3] = Pw; pa[3] = u3.v;
    }

    // O += P V : A = pa (row = q = l31, k = key), B = V^T frag (col = d)
    __builtin_amdgcn_s_setprio(1);
    #pragma unroll
    for (int k4 = 0; k4 < 4; k4++)
      #pragma unroll
      for (int dt = 0; dt < 4; dt++){
        int d = dt * 32 + l31;
        bf16x8 vf = *(const bf16x8*)&Vb[(d * 8 + ((k4 * 2 + hf) ^ (d & 7))) * 8];
        o[dt] = __builtin_amdgcn_mfma_f32_32x32x16_bf16(pa[k4], vf, o[dt], 0, 0, 0);
      }
    __builtin_amdgcn_s_setprio(0);
    cur ^= 1;
  }

  int part = (qt * 8 + bh) * KSPLIT + ks;
  if (lane < 32){
    ml[(size_t)part * 256 + wv * 32 + l31]       = mrow;
    ml[(size_t)part * 256 + 128 + wv * 32 + l31] = lrow;
  }
  // bf16 partials, fully coalesced: group G=(wv*4+g)*4+dt, 4 bf16 per lane =
  // rows q = wv*32 + 8g + 4*hf + (0..3), col d = dt*32 + l31
  ushort* op = opart + (size_t)part * 16384;
  #pragma unroll
  for (int g = 0; g < 4; g++)
    #pragma unroll
    for (int dt = 0; dt < 4; dt++){
      uint2 pk;
      pk.x = cvtpk_bf16(o[dt][4 * g + 0], o[dt][4 * g + 1]);
      pk.y = cvtpk_bf16(o[dt][4 * g + 2], o[dt][4 * g + 3]);
      *(uint2*)&op[((((wv * 4 + g) * 4 + dt) * 64) + lane) * 4] = pk;
    }
}

// ---------------- combine KSPLIT key-split bf16 partials -> bf16 attention out ---
__global__ __launch_bounds__(256) void attn_combine_kernel(
    const ushort* __restrict__ opart, const float* __restrict__ ml,
    ushort* __restrict__ out)
{
  int qt = blockIdx.x, bh = blockIdx.y;
  int b = bh >> 2, hd = bh & 3;
  int tid = threadIdx.x, lane = tid & 63, wq = tid >> 6;
  int l31 = lane & 31, hf = lane >> 5;
  int base = (qt * 8 + bh) * KSPLIT;

  #pragma unroll
  for (int g = 0; g < 4; g++){
    int qb = wq * 32 + 8 * g + 4 * hf;       // 4 consecutive q rows
    float mv[KSPLIT][4], lv[KSPLIT][4];
    #pragma unroll
    for (int p = 0; p < KSPLIT; p++){
      float4 m = *(const float4*)&ml[(size_t)(base + p) * 256 + qb];
      float4 l = *(const float4*)&ml[(size_t)(base + p) * 256 + 128 + qb];
      mv[p][0] = m.x; mv[p][1] = m.y; mv[p][2] = m.z; mv[p][3] = m.w;
      lv[p][0] = l.x; lv[p][1] = l.y; lv[p][2] = l.z; lv[p][3] = l.w;
    }
    float wr[KSPLIT][4], invr[4];
    #pragma unroll
    for (int r = 0; r < 4; r++){
      float mx = mv[0][r];
      #pragma unroll
      for (int p = 1; p < KSPLIT; p++) mx = fmaxf(mx, mv[p][r]);
      float den = 0.f;
      #pragma unroll
      for (int p = 0; p < KSPLIT; p++){
        wr[p][r] = __builtin_amdgcn_exp2f(mv[p][r] - mx);
        den += wr[p][r] * lv[p][r];
      }
      invr[r] = 1.0f / den;
    }
    #pragma unroll
    for (int dt = 0; dt < 4; dt++){
      int idx = (((wq * 4 + g) * 4 + dt) * 64 + lane) * 4;
      float acc[4] = {0.f, 0.f, 0.f, 0.f};
      #pragma unroll
      for (int p = 0; p < KSPLIT; p++){
        union { ushort h[4]; uint2 u; } a;
        a.u = *(const uint2*)&opart[(size_t)(base + p) * 16384 + idx];
        #pragma unroll
        for (int r = 0; r < 4; r++) acc[r] += wr[p][r] * bf2f(a.h[r]);
      }
      #pragma unroll
      for (int r = 0; r < 4; r++){
        int n = qt * 128 + qb + r;
        if (n < NN)
          out[((size_t)(b * NN + n)) * CC + hd * 128 + dt * 32 + l31] = f2bf(acc[r] * invr[r]);
      }
    }
  }
}

// ---------------- depthwise conv k=3 along sequence + exact GELU, bf16 ----------
__global__ __launch_bounds__(256) void dwconv_kernel(
    const ushort* __restrict__ u, const float* __restrict__ w,
    const float* __restrict__ bia, ushort* __restrict__ out)
{
  int g = blockIdx.x * 256 + threadIdx.x;   // 8 channels per thread
  int row = g >> 8;
  int c8 = (g & 255) * 8;
  int n = row & (HH - 1);
  size_t base = (size_t)row * HIDD + c8;
  uint4 z4; z4.x = z4.y = z4.z = z4.w = 0;
  uint4 u1 = *(const uint4*)(u + base);
  uint4 u0 = (n > 0)      ? *(const uint4*)(u + base - HIDD) : z4;
  uint4 u2 = (n < HH - 1) ? *(const uint4*)(u + base + HIDD) : z4;
  const ushort* p0 = (const ushort*)&u0;
  const ushort* p1 = (const ushort*)&u1;
  const ushort* p2 = (const ushort*)&u2;
  union { ushort h[8]; uint4 v; } o;
  #pragma unroll
  for (int k = 0; k < 8; k++){
    int c = c8 + k;
    float acc = bia[c] + w[c * 3] * bf2f(p0[k]) + w[c * 3 + 1] * bf2f(p1[k]) + w[c * 3 + 2] * bf2f(p2[k]);
    o.h[k] = f2bf(gelu_f(acc));
  }
  *(uint4*)(out + base) = o.v;
}

// ---------------- launch ----------------
extern "C" void kernel_launch(void* const* d_in, const int* in_sizes, int n_in,
                              void* d_out, int out_size, void* d_ws, size_t ws_size,
                              hipStream_t stream)
{
  const float* x      = (const float*)d_in[0];
  const float* ln1w   = (const float*)d_in[1];
  const float* ln1b   = (const float*)d_in[2];
  const float* ln2w   = (const float*)d_in[3];
  const float* ln2b   = (const float*)d_in[4];
  const float* q_b    = (const float*)d_in[6];
  const float* kv_b   = (const float*)d_in[8];
  const float* proj_b = (const float*)d_in[10];
  const float* fc1_b  = (const float*)d_in[12];
  const float* dw_w   = (const float*)d_in[13];
  const float* dw_b   = (const float*)d_in[14];
  const float* fc2_b  = (const float*)d_in[16];
  const float* px1_b  = (const float*)d_in[18];
  const float* px2_b  = (const float*)d_in[20];
  const float* gamma1 = (const float*)d_in[21];
  const float* gamma2 = (const float*)d_in[22];
  float* out = (float*)d_out;

  char* ws = (char*)d_ws;
  ushort* wbf = (ushort*)(ws);               //  8,388,608 B  weights bf16
  ushort* lnb = (ushort*)(ws + 8388608);     //  8,519,680 B  ln out
  ushort* qb  = (ushort*)(ws + 16908288);    //  8,519,680 B  Q (pre-scaled)
  ushort* kb  = (ushort*)(ws + 25427968);    //  8,519,680 B  K
  ushort* vtb = (ushort*)(ws + 33947648);    //  8,519,680 B  V^T (bh,d,n)
  ushort* ab  = (ushort*)(ws + 42467328);    //  8,519,680 B  attention out
  // overlay region: opart+ml used by attn/combine, then f1/dg by FFN
  ushort* opart = (ushort*)(ws + 50987008);  // 51,904,512 B (bf16 partials, 6 splits)
  float*  mlb   = (float*)(ws + 102891520);  //  1,622,016 B
  ushort* f1  = (ushort*)(ws + 50987008);    // 33,554,432 B
  ushort* dg  = (ushort*)(ws + 84541440);    // 33,554,432 B
  ushort* sm1 = (ushort*)(ws + 118095872);   //    262,144 B

  ushort* wq    = wbf;              // also covers wkv at +262144 (fused O=1536)
  ushort* wproj = wbf + 786432;
  ushort* wfc1  = wbf + 1048576;
  ushort* wfc2  = wbf + 2097152;
  ushort* wpx1  = wbf + 3145728;
  ushort* wpx2  = wbf + 3670016;

  wconv_kernel<<<4096, 256, 0, stream>>>((const float*)d_in[5], (const float*)d_in[7],
                                         (const float*)d_in[9], (const float*)d_in[11],
                                         (const float*)d_in[15], (const float*)d_in[17],
                                         (const float*)d_in[19], wbf);
  ln_kernel<<<2080, 256, 0, stream>>>(x, ln1w, ln1b, lnb);
  // fused QKV: O = 1536 (q_w ++ kv_w are adjacent in wbf)
  gemm_kernel<128,0,0,3><<<dim3(65, 12), 256, 0, stream>>>(
      lnb, 512, wq, q_b, kv_b, qb, kb, nullptr, nullptr, nullptr, vtb, 512, 1536);
  attn_kernel<<<dim3(33, 8, KSPLIT), 256, 0, stream>>>(qb, kb, vtb, opart, mlb);
  attn_combine_kernel<<<dim3(33, 8), 256, 0, stream>>>(opart, mlb, ab);
  gemm_kernel<64,0,0,2><<<dim3(65, 8), 256, 0, stream>>>(
      ab, 512, wproj, proj_b, nullptr, nullptr, nullptr, out, x, gamma1, nullptr, 512, 512);
  ln_kernel<<<2080, 256, 0, stream>>>(out, ln2w, ln2b, lnb);
  gemm_kernel<128,1,0,0><<<dim3(64, 16), 256, 0, stream>>>(
      lnb, 512, wfc1, fc1_b, nullptr, f1, nullptr, nullptr, nullptr, nullptr, nullptr, 512, 2048);
  dwconv_kernel<<<8192, 256, 0, stream>>>(f1, dw_w, dw_b, dg);
  gemm_kernel<64,0,1,2><<<dim3(64, 8), 256, 0, stream>>>(
      dg, 2048, wfc2, fc2_b, nullptr, nullptr, nullptr, out, out, gamma2, nullptr, 2048, 512);
  gemm_kernel<64,2,0,1><<<dim3(1, 16), 256, 0, stream>>>(
      lnb, 512, wpx1, px1_b, nullptr, sm1, nullptr, nullptr, nullptr, nullptr, nullptr, 512, 1024);
  gemm_kernel<64,0,2,2><<<dim3(1, 8), 256, 0, stream>>>(
      sm1, 1024, wpx2, px2_b, nullptr, nullptr, nullptr, out, out, gamma2, nullptr, 1024, 512);
}